// Round 3
// baseline (2383.628 us; speedup 1.0000x reference)
//
#include <hip/hip_runtime.h>
#include <hip/hip_bf16.h>

// GCN: 3x GraphConv(norm='both') + 4->2 linear + softmax.
// Round 3: bucketed counting-sort CSR build (no random global atomics, no
// line-churn scattered writes), then atomic-free fused pull-gathers.

#define BT 256
#define LOGW 10
#define NPB 1024            // nodes per bucket (must be 4*BT for build scan)
#define CHUNK 16384

// ---------------- round-3 bucketed CSR path ----------------

// Chunked LDS histogram of dst-buckets and src-buckets.
__global__ void bucket_count_kernel(const int* __restrict__ src, const int* __restrict__ dst,
                                    int* __restrict__ bcnt, int* __restrict__ bcnt2,
                                    int E, int K) {
    __shared__ int h1[NPB];
    __shared__ int h2[NPB];
    for (int l = threadIdx.x; l < NPB; l += BT) { h1[l] = 0; h2[l] = 0; }
    __syncthreads();
    int base = blockIdx.x * CHUNK;
    int lim = min(E - base, CHUNK);
    for (int j = threadIdx.x; j < lim; j += BT) {
        atomicAdd(&h1[dst[base + j] >> LOGW], 1);
        atomicAdd(&h2[src[base + j] >> LOGW], 1);
    }
    __syncthreads();
    for (int l = threadIdx.x; l < K; l += BT) {
        int v1 = h1[l]; if (v1) atomicAdd(&bcnt[l], v1);
        int v2 = h2[l]; if (v2) atomicAdd(&bcnt2[l], v2);
    }
}

// Single-block exclusive scan of both bucket-count arrays (K <= 1024).
__global__ void scan_kernel(const int* __restrict__ bcnt, int* __restrict__ gbase, int* __restrict__ cur,
                            const int* __restrict__ bcnt2, int* __restrict__ gbase2, int* __restrict__ cur2,
                            int K) {
    __shared__ int wtot[16];
    int t = threadIdx.x, lane = t & 63, w = t >> 6;

    int v = (t < K) ? bcnt[t] : 0;
    int s = v;
    #pragma unroll
    for (int o = 1; o < 64; o <<= 1) { int u = __shfl_up(s, o); if (lane >= o) s += u; }
    if (lane == 63) wtot[w] = s;
    __syncthreads();
    int wpre = 0;
    for (int j = 0; j < w; ++j) wpre += wtot[j];
    int excl = wpre + s - v;
    if (t < K) { gbase[t] = excl; cur[t] = excl; }
    if (t == 1023) gbase[K] = wpre + s;   // grand total = E
    __syncthreads();

    v = (t < K) ? bcnt2[t] : 0;
    s = v;
    #pragma unroll
    for (int o = 1; o < 64; o <<= 1) { int u = __shfl_up(s, o); if (lane >= o) s += u; }
    if (lane == 63) wtot[w] = s;
    __syncthreads();
    wpre = 0;
    for (int j = 0; j < w; ++j) wpre += wtot[j];
    excl = wpre + s - v;
    if (t < K) { gbase2[t] = excl; cur2[t] = excl; }
    if (t == 1023) gbase2[K] = wpre + s;
}

// Partition edges: P bucketed by dst (packed src<<10 | dst_local),
// P2 bucketed by src (src_local as ushort). Writes are sequential per bucket.
__global__ void partition_kernel(const int* __restrict__ src, const int* __restrict__ dst,
                                 int* __restrict__ cur, int* __restrict__ cur2,
                                 int* __restrict__ P, unsigned short* __restrict__ P2, int E) {
    int e = blockIdx.x * blockDim.x + threadIdx.x;
    if (e < E) {
        int s = src[e], d = dst[e];
        int p = atomicAdd(&cur[d >> LOGW], 1);
        P[p] = (s << LOGW) | (d & (NPB - 1));
        int q = atomicAdd(&cur2[s >> LOGW], 1);
        P2[q] = (unsigned short)(s & (NPB - 1));
    }
}

// Per-bucket src-degree histogram -> degs (dense writes, no random atomics).
__global__ void src_deg_kernel(const unsigned short* __restrict__ P2, const int* __restrict__ gbase2,
                               int* __restrict__ degs, int N) {
    __shared__ int hist[NPB];
    int b = blockIdx.x;
    for (int l = threadIdx.x; l < NPB; l += BT) hist[l] = 0;
    __syncthreads();
    int pb = gbase2[b], sz = gbase2[b + 1] - pb;
    for (int j = threadIdx.x; j < sz; j += BT) atomicAdd(&hist[P2[pb + j]], 1);
    __syncthreads();
    int vb = b * NPB;
    for (int l = threadIdx.x; l < NPB; l += BT) {
        int v = vb + l;
        if (v < N) degs[v] = hist[l];
    }
}

// ns from degs (stored in sx slot), sx = x*ns overwrites it in place.
__global__ void finalize2_kernel(const float* __restrict__ x, float* __restrict__ ns,
                                 float* __restrict__ sx_deg, int N) {
    int i = blockIdx.x * blockDim.x + threadIdx.x;
    if (i < N) {
        int d = ((const int*)sx_deg)[i];
        float nsv = d > 0 ? rsqrtf((float)d) : 0.f;
        ns[i] = nsv;
        sx_deg[i] = x[i] * nsv;
    }
}

// Per-bucket: LDS histogram + block scan -> endp/nd, then in-bucket scatter of eidx.
__global__ void build_kernel(const int* __restrict__ P, const int* __restrict__ gbase,
                             int* __restrict__ eidx, int* __restrict__ endp,
                             float* __restrict__ nd, int N) {
    __shared__ int hist[NPB];
    __shared__ int wtot[BT / 64];
    int b = blockIdx.x;
    int t = threadIdx.x, lane = t & 63, w = t >> 6;
    for (int l = t; l < NPB; l += BT) hist[l] = 0;
    __syncthreads();
    int gb = gbase[b], sz = gbase[b + 1] - gb;
    for (int j = t; j < sz; j += BT) atomicAdd(&hist[P[gb + j] & (NPB - 1)], 1);
    __syncthreads();
    // exclusive block scan over hist[0..NPB-1], 4 consecutive per thread
    int l0 = t * 4;
    int h0 = hist[l0], h1 = hist[l0 + 1], h2 = hist[l0 + 2], h3 = hist[l0 + 3];
    int own = h0 + h1 + h2 + h3;
    int s = own;
    #pragma unroll
    for (int o = 1; o < 64; o <<= 1) { int u = __shfl_up(s, o); if (lane >= o) s += u; }
    if (lane == 63) wtot[w] = s;
    __syncthreads();
    int wpre = 0;
    for (int j = 0; j < w; ++j) wpre += wtot[j];
    int e0 = wpre + s - own;
    int e1 = e0 + h0, e2 = e1 + h1, e3 = e2 + h2;
    int vb = b * NPB;
    if (vb + l0     < N) { endp[vb + l0]     = gb + e1;      nd[vb + l0]     = h0 > 0 ? rsqrtf((float)h0) : 0.f; }
    if (vb + l0 + 1 < N) { endp[vb + l0 + 1] = gb + e2;      nd[vb + l0 + 1] = h1 > 0 ? rsqrtf((float)h1) : 0.f; }
    if (vb + l0 + 2 < N) { endp[vb + l0 + 2] = gb + e3;      nd[vb + l0 + 2] = h2 > 0 ? rsqrtf((float)h2) : 0.f; }
    if (vb + l0 + 3 < N) { endp[vb + l0 + 3] = gb + e3 + h3; nd[vb + l0 + 3] = h3 > 0 ? rsqrtf((float)h3) : 0.f; }
    __syncthreads();
    hist[l0] = e0; hist[l0 + 1] = e1; hist[l0 + 2] = e2; hist[l0 + 3] = e3;
    __syncthreads();
    for (int j = t; j < sz; j += BT) {
        int val = P[gb + j];
        int p = atomicAdd(&hist[val & (NPB - 1)], 1);
        eidx[gb + p] = val >> LOGW;
    }
}

// Gathers: contiguous CSR, start = endp[v-1].
__global__ void g1_kernel(const float* __restrict__ sx, const int* __restrict__ eidx,
                          const int* __restrict__ endp,
                          const float* __restrict__ ns, const float* __restrict__ nd,
                          const float* __restrict__ W1, const float* __restrict__ b1,
                          const float* __restrict__ W2, float4* __restrict__ A, int N) {
    int i = blockIdx.x * blockDim.x + threadIdx.x;
    if (i >= N) return;
    int e = endp[i];
    int s0i = (i == 0) ? 0 : endp[i - 1];
    float sum = 0.f;
    for (int k = s0i; k < e; ++k) sum += sx[eidx[k]];
    float tt = sum * nd[i];
    float nsv = ns[i];
    float x0 = fmaxf(tt * W1[0] + b1[0], 0.f) * nsv;
    float x1 = fmaxf(tt * W1[1] + b1[1], 0.f) * nsv;
    float x2 = fmaxf(tt * W1[2] + b1[2], 0.f) * nsv;
    float x3 = fmaxf(tt * W1[3] + b1[3], 0.f) * nsv;
    float4 o;
    o.x = x0*W2[0] + x1*W2[4] + x2*W2[8]  + x3*W2[12];
    o.y = x0*W2[1] + x1*W2[5] + x2*W2[9]  + x3*W2[13];
    o.z = x0*W2[2] + x1*W2[6] + x2*W2[10] + x3*W2[14];
    o.w = x0*W2[3] + x1*W2[7] + x2*W2[11] + x3*W2[15];
    A[i] = o;
}

__global__ void g4_kernel(const float4* __restrict__ H, const int* __restrict__ eidx,
                          const int* __restrict__ endp,
                          const float* __restrict__ ns, const float* __restrict__ nd,
                          const float* __restrict__ b, const float* __restrict__ W,
                          float4* __restrict__ out, int N) {
    int i = blockIdx.x * blockDim.x + threadIdx.x;
    if (i >= N) return;
    int e = endp[i];
    int st = (i == 0) ? 0 : endp[i - 1];
    float s0 = 0.f, s1 = 0.f, s2 = 0.f, s3 = 0.f;
    for (int k = st; k < e; ++k) {
        float4 v = H[eidx[k]];
        s0 += v.x; s1 += v.y; s2 += v.z; s3 += v.w;
    }
    float nv = nd[i], nsv = ns[i];
    float x0 = fmaxf(s0 * nv + b[0], 0.f) * nsv;
    float x1 = fmaxf(s1 * nv + b[1], 0.f) * nsv;
    float x2 = fmaxf(s2 * nv + b[2], 0.f) * nsv;
    float x3 = fmaxf(s3 * nv + b[3], 0.f) * nsv;
    float4 o;
    o.x = x0*W[0] + x1*W[4] + x2*W[8]  + x3*W[12];
    o.y = x0*W[1] + x1*W[5] + x2*W[9]  + x3*W[13];
    o.z = x0*W[2] + x1*W[6] + x2*W[10] + x3*W[14];
    o.w = x0*W[3] + x1*W[7] + x2*W[11] + x3*W[15];
    out[i] = o;
}

__global__ void gF_kernel(const float4* __restrict__ H, const int* __restrict__ eidx,
                          const int* __restrict__ endp, const float* __restrict__ nd,
                          const float* __restrict__ b, const float* __restrict__ Wl,
                          const float* __restrict__ bl, float2* __restrict__ out, int N) {
    int i = blockIdx.x * blockDim.x + threadIdx.x;
    if (i >= N) return;
    int e = endp[i];
    int st = (i == 0) ? 0 : endp[i - 1];
    float s0 = 0.f, s1 = 0.f, s2 = 0.f, s3 = 0.f;
    for (int k = st; k < e; ++k) {
        float4 v = H[eidx[k]];
        s0 += v.x; s1 += v.y; s2 += v.z; s3 += v.w;
    }
    float nv = nd[i];
    float x0 = s0 * nv + b[0];
    float x1 = s1 * nv + b[1];
    float x2 = s2 * nv + b[2];
    float x3 = s3 * nv + b[3];
    float z0 = x0*Wl[0] + x1*Wl[2] + x2*Wl[4] + x3*Wl[6] + bl[0];
    float z1 = x0*Wl[1] + x1*Wl[3] + x2*Wl[5] + x3*Wl[7] + bl[1];
    float m  = fmaxf(z0, z1);
    float e0 = expf(z0 - m), e1 = expf(z1 - m);
    float inv = 1.f / (e0 + e1);
    out[i] = make_float2(e0 * inv, e1 * inv);
}

// ---------------- round-2 fallback (atomic-cursor CSR) ----------------

__global__ void count_kernel(const int* __restrict__ src, const int* __restrict__ dst,
                             int* __restrict__ degs, int* __restrict__ degd, int E) {
    int i = blockIdx.x * blockDim.x + threadIdx.x;
    if (i < E) { atomicAdd(&degs[src[i]], 1); atomicAdd(&degd[dst[i]], 1); }
}

__global__ void finalize_alloc_kernel(const int* __restrict__ degs, const int* __restrict__ degd,
                                      const float* __restrict__ x,
                                      float* __restrict__ ns, float* __restrict__ nd,
                                      float* __restrict__ sx, int* __restrict__ start,
                                      int* __restrict__ cursor, int N) {
    int i = blockIdx.x * blockDim.x + threadIdx.x;
    int lane = threadIdx.x & 63;
    int dd = 0;
    if (i < N) {
        int ds = degs[i];
        float nsv = ds > 0 ? rsqrtf((float)ds) : 0.f;
        ns[i] = nsv;
        dd = degd[i];
        nd[i] = dd > 0 ? rsqrtf((float)dd) : 0.f;
        sx[i] = x[i] * nsv;
    }
    int pre = dd;
    #pragma unroll
    for (int off = 1; off < 64; off <<= 1) {
        int t = __shfl_up(pre, off);
        if (lane >= off) pre += t;
    }
    int total = __shfl(pre, 63);
    int base = 0;
    if (lane == 63 && total > 0) base = atomicAdd(cursor, total);
    base = __shfl(base, 63);
    if (i < N) start[i] = base + pre - dd;
}

__global__ void fill_kernel(const int* __restrict__ src, const int* __restrict__ dst,
                            int* __restrict__ start, int* __restrict__ eidx, int E) {
    int i = blockIdx.x * blockDim.x + threadIdx.x;
    if (i < E) {
        int p = atomicAdd(&start[dst[i]], 1);
        eidx[p] = src[i];
    }
}

__global__ void fb_g1(const float* __restrict__ sx, const int* __restrict__ eidx,
                      const int* __restrict__ endp, const int* __restrict__ deg,
                      const float* __restrict__ ns, const float* __restrict__ nd,
                      const float* __restrict__ W1, const float* __restrict__ b1,
                      const float* __restrict__ W2, float4* __restrict__ A, int N) {
    int i = blockIdx.x * blockDim.x + threadIdx.x;
    if (i >= N) return;
    int e = endp[i], d = deg[i];
    float sum = 0.f;
    for (int k = e - d; k < e; ++k) sum += sx[eidx[k]];
    float t = sum * nd[i];
    float nsv = ns[i];
    float x0 = fmaxf(t * W1[0] + b1[0], 0.f) * nsv;
    float x1 = fmaxf(t * W1[1] + b1[1], 0.f) * nsv;
    float x2 = fmaxf(t * W1[2] + b1[2], 0.f) * nsv;
    float x3 = fmaxf(t * W1[3] + b1[3], 0.f) * nsv;
    float4 o;
    o.x = x0*W2[0] + x1*W2[4] + x2*W2[8]  + x3*W2[12];
    o.y = x0*W2[1] + x1*W2[5] + x2*W2[9]  + x3*W2[13];
    o.z = x0*W2[2] + x1*W2[6] + x2*W2[10] + x3*W2[14];
    o.w = x0*W2[3] + x1*W2[7] + x2*W2[11] + x3*W2[15];
    A[i] = o;
}

__global__ void fb_g4(const float4* __restrict__ H, const int* __restrict__ eidx,
                      const int* __restrict__ endp, const int* __restrict__ deg,
                      const float* __restrict__ ns, const float* __restrict__ nd,
                      const float* __restrict__ b, const float* __restrict__ W,
                      float4* __restrict__ out, int N) {
    int i = blockIdx.x * blockDim.x + threadIdx.x;
    if (i >= N) return;
    int e = endp[i], d = deg[i];
    float s0 = 0.f, s1 = 0.f, s2 = 0.f, s3 = 0.f;
    for (int k = e - d; k < e; ++k) {
        float4 v = H[eidx[k]];
        s0 += v.x; s1 += v.y; s2 += v.z; s3 += v.w;
    }
    float nv = nd[i], nsv = ns[i];
    float x0 = fmaxf(s0 * nv + b[0], 0.f) * nsv;
    float x1 = fmaxf(s1 * nv + b[1], 0.f) * nsv;
    float x2 = fmaxf(s2 * nv + b[2], 0.f) * nsv;
    float x3 = fmaxf(s3 * nv + b[3], 0.f) * nsv;
    float4 o;
    o.x = x0*W[0] + x1*W[4] + x2*W[8]  + x3*W[12];
    o.y = x0*W[1] + x1*W[5] + x2*W[9]  + x3*W[13];
    o.z = x0*W[2] + x1*W[6] + x2*W[10] + x3*W[14];
    o.w = x0*W[3] + x1*W[7] + x2*W[11] + x3*W[15];
    out[i] = o;
}

__global__ void fb_gF(const float4* __restrict__ H, const int* __restrict__ eidx,
                      const int* __restrict__ endp, const int* __restrict__ deg,
                      const float* __restrict__ nd, const float* __restrict__ b,
                      const float* __restrict__ Wl, const float* __restrict__ bl,
                      float2* __restrict__ out, int N) {
    int i = blockIdx.x * blockDim.x + threadIdx.x;
    if (i >= N) return;
    int e = endp[i], d = deg[i];
    float s0 = 0.f, s1 = 0.f, s2 = 0.f, s3 = 0.f;
    for (int k = e - d; k < e; ++k) {
        float4 v = H[eidx[k]];
        s0 += v.x; s1 += v.y; s2 += v.z; s3 += v.w;
    }
    float nv = nd[i];
    float x0 = s0 * nv + b[0];
    float x1 = s1 * nv + b[1];
    float x2 = s2 * nv + b[2];
    float x3 = s3 * nv + b[3];
    float z0 = x0*Wl[0] + x1*Wl[2] + x2*Wl[4] + x3*Wl[6] + bl[0];
    float z1 = x0*Wl[1] + x1*Wl[3] + x2*Wl[5] + x3*Wl[7] + bl[1];
    float m  = fmaxf(z0, z1);
    float e0 = expf(z0 - m), e1 = expf(z1 - m);
    float inv = 1.f / (e0 + e1);
    out[i] = make_float2(e0 * inv, e1 * inv);
}

extern "C" void kernel_launch(void* const* d_in, const int* in_sizes, int n_in,
                              void* d_out, int out_size, void* d_ws, size_t ws_size,
                              hipStream_t stream) {
    const float* in_feat = (const float*)d_in[0];
    const int*   src     = (const int*)d_in[1];
    const int*   dst     = (const int*)d_in[2];
    const float* W1 = (const float*)d_in[3];
    const float* b1 = (const float*)d_in[4];
    const float* W2 = (const float*)d_in[5];
    const float* b2 = (const float*)d_in[6];
    const float* W3 = (const float*)d_in[7];
    const float* b3 = (const float*)d_in[8];
    const float* Wl = (const float*)d_in[9];
    const float* bl = (const float*)d_in[10];

    const int N = in_sizes[0];
    const int E = in_sizes[1];

    const int gridN = (N + BT - 1) / BT;
    const int gridE = (E + BT - 1) / BT;

    const int K = (N + NPB - 1) / NPB;     // buckets
    const size_t uN = (size_t)N, uE = (size_t)E;
    const size_t Uints = (uE > 8 * uN ? uE : 8 * uN);
    // layout (ints/floats, 4B each): ns|nd|sx|endp | eidx(E) | U | counters(6*1056)
    const size_t need3 = (4 * uN + uE + Uints + 6 * 1056) * 4;

    if (ws_size >= need3 && N <= (1 << 20) && K <= 1024) {
        float* ws   = (float*)d_ws;
        float* ns   = ws;
        float* nd   = ws + uN;
        float* sx   = ws + 2 * uN;            // holds degs (int) until finalize2
        int*   endp = (int*)(ws + 3 * uN);
        int*   eidx = (int*)(ws + 4 * uN);    // ushort P2 lives here first
        int*   U    = (int*)(ws + 4 * uN + uE);
        int*   ctr  = U + Uints;
        int* bcnt   = ctr;
        int* cur    = ctr + 1056;
        int* gbase  = ctr + 2112;
        int* bcnt2  = ctr + 3168;
        int* cur2   = ctr + 4224;
        int* gbase2 = ctr + 5280;
        int*    P   = U;                       // E ints
        float4* A   = (float4*)U;              // 4N floats (after P dead)
        float4* B4  = (float4*)(U + 4 * uN);   // 4N floats
        unsigned short* P2 = (unsigned short*)eidx;

        hipMemsetAsync(ctr, 0, 6 * 1056 * sizeof(int), stream);
        bucket_count_kernel<<<(E + CHUNK - 1) / CHUNK, BT, 0, stream>>>(src, dst, bcnt, bcnt2, E, K);
        scan_kernel<<<1, 1024, 0, stream>>>(bcnt, gbase, cur, bcnt2, gbase2, cur2, K);
        partition_kernel<<<gridE, BT, 0, stream>>>(src, dst, cur, cur2, P, P2, E);
        src_deg_kernel<<<K, BT, 0, stream>>>(P2, gbase2, (int*)sx, N);
        finalize2_kernel<<<gridN, BT, 0, stream>>>(in_feat, ns, sx, N);
        build_kernel<<<K, BT, 0, stream>>>(P, gbase, eidx, endp, nd, N);
        g1_kernel<<<gridN, BT, 0, stream>>>(sx, eidx, endp, ns, nd, W1, b1, W2, A, N);
        g4_kernel<<<gridN, BT, 0, stream>>>(A, eidx, endp, ns, nd, b2, W3, B4, N);
        gF_kernel<<<gridN, BT, 0, stream>>>(B4, eidx, endp, nd, b3, Wl, bl, (float2*)d_out, N);
        return;
    }

    // ---------- round-2 fallback ----------
    size_t need2 = (13 * uN + uE + 16) * 4;
    if (ws_size >= need2) {
        float* ws   = (float*)d_ws;
        float* ns   = ws;
        float* nd   = ws + uN;
        float* sx   = ws + 2 * uN;
        int*   deg  = (int*)(ws + 3 * uN);
        int*   start= (int*)(ws + 4 * uN);
        float4* A   = (float4*)(ws + 5 * uN);
        float4* B   = (float4*)(ws + 9 * uN);
        int*   eidx = (int*)(ws + 13 * uN);
        int*   cursor = eidx + uE;
        int*   degs = (int*)A;

        hipMemsetAsync(deg, 0, uN * sizeof(int), stream);
        hipMemsetAsync(degs, 0, uN * sizeof(int), stream);
        hipMemsetAsync(cursor, 0, sizeof(int), stream);
        count_kernel<<<gridE, BT, 0, stream>>>(src, dst, degs, deg, E);
        finalize_alloc_kernel<<<gridN, BT, 0, stream>>>(degs, deg, in_feat, ns, nd, sx, start, cursor, N);
        fill_kernel<<<gridE, BT, 0, stream>>>(src, dst, start, eidx, E);
        fb_g1<<<gridN, BT, 0, stream>>>(sx, eidx, start, deg, ns, nd, W1, b1, W2, A, N);
        fb_g4<<<gridN, BT, 0, stream>>>(A, eidx, start, deg, ns, nd, b2, W3, B, N);
        fb_gF<<<gridN, BT, 0, stream>>>(B, eidx, start, deg, nd, b3, Wl, bl, (float2*)d_out, N);
    }
}

// Round 4
// 785.769 us; speedup vs baseline: 3.0335x; 3.0335x over previous
//
#include <hip/hip_runtime.h>
#include <hip/hip_bf16.h>

// GCN: 3x GraphConv(norm='both') + 4->2 linear + softmax.
// Round 4: radix-style edge partition with block-private destination ranges
// (no cross-XCD line sharing), then per-bucket LDS-resident aggregation
// (bucket = 1024 nodes -> accumulators in LDS; no CSR, no global scatter).

#define BT 256
#define LOGW 10
#define NPB 1024            // nodes per bucket
#define KMAX 1024           // max buckets
#define CH 32768            // edges per hist/rank block

// ---------------- round-4 bucketed path ----------------

// Per-block LDS histograms of dst-bucket and src-bucket -> column-major matrices.
__global__ void hist_kernel(const int* __restrict__ src, const int* __restrict__ dst,
                            int* __restrict__ M1, int* __restrict__ M2,
                            int E, int K, int NBLK) {
    __shared__ int h1[KMAX];
    __shared__ int h2[KMAX];
    for (int l = threadIdx.x; l < K; l += BT) { h1[l] = 0; h2[l] = 0; }
    __syncthreads();
    int base = blockIdx.x * CH;
    int lim = min(E - base, CH);
    for (int j = threadIdx.x; j < lim; j += BT) {
        atomicAdd(&h1[dst[base + j] >> LOGW], 1);
        atomicAdd(&h2[src[base + j] >> LOGW], 1);
    }
    __syncthreads();
    for (int l = threadIdx.x; l < K; l += BT) {
        M1[(size_t)l * NBLK + blockIdx.x] = h1[l];
        M2[(size_t)l * NBLK + blockIdx.x] = h2[l];
    }
}

// One wave per bucket: exclusive scan along the block axis (in place), row sum out.
__global__ void rowscan_kernel(int* __restrict__ M1, int* __restrict__ M2,
                               int* __restrict__ bsum1, int* __restrict__ bsum2, int NBLK) {
    int b = blockIdx.x, lane = threadIdx.x;   // 64 threads
    size_t rb = (size_t)b * NBLK;
    int carry = 0;
    for (int base = 0; base < NBLK; base += 64) {
        int idx = base + lane;
        int v = (idx < NBLK) ? M1[rb + idx] : 0;
        int s = v;
        #pragma unroll
        for (int o = 1; o < 64; o <<= 1) { int u = __shfl_up(s, o); if (lane >= o) s += u; }
        if (idx < NBLK) M1[rb + idx] = carry + s - v;
        carry += __shfl(s, 63);
    }
    if (lane == 0) bsum1[b] = carry;
    carry = 0;
    for (int base = 0; base < NBLK; base += 64) {
        int idx = base + lane;
        int v = (idx < NBLK) ? M2[rb + idx] : 0;
        int s = v;
        #pragma unroll
        for (int o = 1; o < 64; o <<= 1) { int u = __shfl_up(s, o); if (lane >= o) s += u; }
        if (idx < NBLK) M2[rb + idx] = carry + s - v;
        carry += __shfl(s, 63);
    }
    if (lane == 0) bsum2[b] = carry;
}

// Single-block exclusive scan of both bucket-total arrays (K <= 1024).
__global__ void scanK_kernel(const int* __restrict__ bsum1, int* __restrict__ bbase1,
                             const int* __restrict__ bsum2, int* __restrict__ bbase2, int K) {
    __shared__ int wtot[16];
    int t = threadIdx.x, lane = t & 63, w = t >> 6;

    int v = (t < K) ? bsum1[t] : 0;
    int s = v;
    #pragma unroll
    for (int o = 1; o < 64; o <<= 1) { int u = __shfl_up(s, o); if (lane >= o) s += u; }
    if (lane == 63) wtot[w] = s;
    __syncthreads();
    int wpre = 0;
    for (int j = 0; j < w; ++j) wpre += wtot[j];
    if (t < K) bbase1[t] = wpre + s - v;
    if (t == 1023) bbase1[K] = wpre + s;
    __syncthreads();

    v = (t < K) ? bsum2[t] : 0;
    s = v;
    #pragma unroll
    for (int o = 1; o < 64; o <<= 1) { int u = __shfl_up(s, o); if (lane >= o) s += u; }
    if (lane == 63) wtot[w] = s;
    __syncthreads();
    wpre = 0;
    for (int j = 0; j < w; ++j) wpre += wtot[j];
    if (t < K) bbase2[t] = wpre + s - v;
    if (t == 1023) bbase2[K] = wpre + s;
}

// Re-read edges; each block writes into its exclusive per-bucket ranges.
__global__ void rank_kernel(const int* __restrict__ src, const int* __restrict__ dst,
                            const int* __restrict__ M1, const int* __restrict__ M2,
                            const int* __restrict__ bbase1, const int* __restrict__ bbase2,
                            int* __restrict__ P, unsigned short* __restrict__ P2,
                            int E, int K, int NBLK) {
    __shared__ int c1[KMAX];
    __shared__ int c2[KMAX];
    int blk = blockIdx.x;
    for (int l = threadIdx.x; l < K; l += BT) {
        c1[l] = bbase1[l] + M1[(size_t)l * NBLK + blk];
        c2[l] = bbase2[l] + M2[(size_t)l * NBLK + blk];
    }
    __syncthreads();
    int base = blk * CH;
    int lim = min(E - base, CH);
    for (int j = threadIdx.x; j < lim; j += BT) {
        int s = src[base + j], d = dst[base + j];
        int p = atomicAdd(&c1[d >> LOGW], 1);
        P[p] = (s << LOGW) | (d & (NPB - 1));
        int q = atomicAdd(&c2[s >> LOGW], 1);
        P2[q] = (unsigned short)(s & (NPB - 1));
    }
}

// Per-src-bucket histogram -> ns = outdeg^{-1/2}, sx = x*ns (dense writes).
__global__ void sdeg_kernel(const unsigned short* __restrict__ P2, const int* __restrict__ bbase2,
                            const float* __restrict__ x,
                            float* __restrict__ ns, float* __restrict__ sx, int N) {
    __shared__ int h[NPB];
    int b = blockIdx.x;
    for (int l = threadIdx.x; l < NPB; l += BT) h[l] = 0;
    __syncthreads();
    int gb = bbase2[b], ge = bbase2[b + 1];
    for (int j = gb + threadIdx.x; j < ge; j += BT) atomicAdd(&h[P2[j]], 1);
    __syncthreads();
    int vb = b << LOGW;
    for (int l = threadIdx.x; l < NPB; l += BT) {
        int v = vb + l;
        if (v < N) {
            int d = h[l];
            float nsv = d > 0 ? rsqrtf((float)d) : 0.f;
            ns[v] = nsv;
            sx[v] = x[v] * nsv;
        }
    }
}

// Layer 1: per-bucket scalar accumulation of sx[src] + in-degree count.
// Stores nd for later layers. Epilogue: *nd+b1, relu, *ns, @W2 -> A.
__global__ void g1_kernel(const int* __restrict__ P, const int* __restrict__ bbase1,
                          const float* __restrict__ sx, const float* __restrict__ ns,
                          float* __restrict__ nd,
                          const float* __restrict__ W1, const float* __restrict__ b1,
                          const float* __restrict__ W2, float4* __restrict__ A, int N) {
    __shared__ float acc[NPB];
    __shared__ int cnt[NPB];
    int b = blockIdx.x;
    for (int l = threadIdx.x; l < NPB; l += BT) { acc[l] = 0.f; cnt[l] = 0; }
    __syncthreads();
    int gb = bbase1[b], ge = bbase1[b + 1];
    for (int j = gb + threadIdx.x; j < ge; j += BT) {
        int val = P[j];
        int l = val & (NPB - 1);
        atomicAdd(&acc[l], sx[val >> LOGW]);
        atomicAdd(&cnt[l], 1);
    }
    __syncthreads();
    int vb = b << LOGW;
    for (int l = threadIdx.x; l < NPB; l += BT) {
        int v = vb + l;
        if (v < N) {
            int h = cnt[l];
            float ndv = h > 0 ? rsqrtf((float)h) : 0.f;
            nd[v] = ndv;
            float tt = acc[l] * ndv;
            float nsv = ns[v];
            float x0 = fmaxf(tt * W1[0] + b1[0], 0.f) * nsv;
            float x1 = fmaxf(tt * W1[1] + b1[1], 0.f) * nsv;
            float x2 = fmaxf(tt * W1[2] + b1[2], 0.f) * nsv;
            float x3 = fmaxf(tt * W1[3] + b1[3], 0.f) * nsv;
            float4 o;
            o.x = x0*W2[0] + x1*W2[4] + x2*W2[8]  + x3*W2[12];
            o.y = x0*W2[1] + x1*W2[5] + x2*W2[9]  + x3*W2[13];
            o.z = x0*W2[2] + x1*W2[6] + x2*W2[10] + x3*W2[14];
            o.w = x0*W2[3] + x1*W2[7] + x2*W2[11] + x3*W2[15];
            A[v] = o;
        }
    }
}

// Middle layer: per-bucket float4 accumulation. Epilogue: *nd+b, relu, *ns, @W.
__global__ void g4_kernel(const int* __restrict__ P, const int* __restrict__ bbase1,
                          const float4* __restrict__ H, const float* __restrict__ ns,
                          const float* __restrict__ nd,
                          const float* __restrict__ bb, const float* __restrict__ W,
                          float4* __restrict__ out, int N) {
    __shared__ float acc[NPB * 4];
    int b = blockIdx.x;
    for (int l = threadIdx.x; l < NPB * 4; l += BT) acc[l] = 0.f;
    __syncthreads();
    int gb = bbase1[b], ge = bbase1[b + 1];
    for (int j = gb + threadIdx.x; j < ge; j += BT) {
        int val = P[j];
        float4 v = H[val >> LOGW];
        int l4 = (val & (NPB - 1)) * 4;
        atomicAdd(&acc[l4 + 0], v.x);
        atomicAdd(&acc[l4 + 1], v.y);
        atomicAdd(&acc[l4 + 2], v.z);
        atomicAdd(&acc[l4 + 3], v.w);
    }
    __syncthreads();
    int vb = b << LOGW;
    for (int l = threadIdx.x; l < NPB; l += BT) {
        int v = vb + l;
        if (v < N) {
            float ndv = nd[v], nsv = ns[v];
            float x0 = fmaxf(acc[l*4+0] * ndv + bb[0], 0.f) * nsv;
            float x1 = fmaxf(acc[l*4+1] * ndv + bb[1], 0.f) * nsv;
            float x2 = fmaxf(acc[l*4+2] * ndv + bb[2], 0.f) * nsv;
            float x3 = fmaxf(acc[l*4+3] * ndv + bb[3], 0.f) * nsv;
            float4 o;
            o.x = x0*W[0] + x1*W[4] + x2*W[8]  + x3*W[12];
            o.y = x0*W[1] + x1*W[5] + x2*W[9]  + x3*W[13];
            o.z = x0*W[2] + x1*W[6] + x2*W[10] + x3*W[14];
            o.w = x0*W[3] + x1*W[7] + x2*W[11] + x3*W[15];
            out[v] = o;
        }
    }
}

// Final layer: accumulation + epilogue (no relu) + [4,2] linear + softmax.
__global__ void gF_kernel(const int* __restrict__ P, const int* __restrict__ bbase1,
                          const float4* __restrict__ H, const float* __restrict__ nd,
                          const float* __restrict__ bb, const float* __restrict__ Wl,
                          const float* __restrict__ bl, float2* __restrict__ out, int N) {
    __shared__ float acc[NPB * 4];
    int b = blockIdx.x;
    for (int l = threadIdx.x; l < NPB * 4; l += BT) acc[l] = 0.f;
    __syncthreads();
    int gb = bbase1[b], ge = bbase1[b + 1];
    for (int j = gb + threadIdx.x; j < ge; j += BT) {
        int val = P[j];
        float4 v = H[val >> LOGW];
        int l4 = (val & (NPB - 1)) * 4;
        atomicAdd(&acc[l4 + 0], v.x);
        atomicAdd(&acc[l4 + 1], v.y);
        atomicAdd(&acc[l4 + 2], v.z);
        atomicAdd(&acc[l4 + 3], v.w);
    }
    __syncthreads();
    int vb = b << LOGW;
    for (int l = threadIdx.x; l < NPB; l += BT) {
        int v = vb + l;
        if (v < N) {
            float ndv = nd[v];
            float x0 = acc[l*4+0] * ndv + bb[0];
            float x1 = acc[l*4+1] * ndv + bb[1];
            float x2 = acc[l*4+2] * ndv + bb[2];
            float x3 = acc[l*4+3] * ndv + bb[3];
            float z0 = x0*Wl[0] + x1*Wl[2] + x2*Wl[4] + x3*Wl[6] + bl[0];
            float z1 = x0*Wl[1] + x1*Wl[3] + x2*Wl[5] + x3*Wl[7] + bl[1];
            float m  = fmaxf(z0, z1);
            float e0 = expf(z0 - m), e1 = expf(z1 - m);
            float inv = 1.f / (e0 + e1);
            out[v] = make_float2(e0 * inv, e1 * inv);
        }
    }
}

// ---------------- round-2 fallback (atomic-cursor CSR) ----------------

__global__ void count_kernel(const int* __restrict__ src, const int* __restrict__ dst,
                             int* __restrict__ degs, int* __restrict__ degd, int E) {
    int i = blockIdx.x * blockDim.x + threadIdx.x;
    if (i < E) { atomicAdd(&degs[src[i]], 1); atomicAdd(&degd[dst[i]], 1); }
}

__global__ void finalize_alloc_kernel(const int* __restrict__ degs, const int* __restrict__ degd,
                                      const float* __restrict__ x,
                                      float* __restrict__ ns, float* __restrict__ nd,
                                      float* __restrict__ sx, int* __restrict__ start,
                                      int* __restrict__ cursor, int N) {
    int i = blockIdx.x * blockDim.x + threadIdx.x;
    int lane = threadIdx.x & 63;
    int dd = 0;
    if (i < N) {
        int ds = degs[i];
        float nsv = ds > 0 ? rsqrtf((float)ds) : 0.f;
        ns[i] = nsv;
        dd = degd[i];
        nd[i] = dd > 0 ? rsqrtf((float)dd) : 0.f;
        sx[i] = x[i] * nsv;
    }
    int pre = dd;
    #pragma unroll
    for (int off = 1; off < 64; off <<= 1) {
        int t = __shfl_up(pre, off);
        if (lane >= off) pre += t;
    }
    int total = __shfl(pre, 63);
    int base = 0;
    if (lane == 63 && total > 0) base = atomicAdd(cursor, total);
    base = __shfl(base, 63);
    if (i < N) start[i] = base + pre - dd;
}

__global__ void fill_kernel(const int* __restrict__ src, const int* __restrict__ dst,
                            int* __restrict__ start, int* __restrict__ eidx, int E) {
    int i = blockIdx.x * blockDim.x + threadIdx.x;
    if (i < E) {
        int p = atomicAdd(&start[dst[i]], 1);
        eidx[p] = src[i];
    }
}

__global__ void fb_g1(const float* __restrict__ sx, const int* __restrict__ eidx,
                      const int* __restrict__ endp, const int* __restrict__ deg,
                      const float* __restrict__ ns, const float* __restrict__ nd,
                      const float* __restrict__ W1, const float* __restrict__ b1,
                      const float* __restrict__ W2, float4* __restrict__ A, int N) {
    int i = blockIdx.x * blockDim.x + threadIdx.x;
    if (i >= N) return;
    int e = endp[i], d = deg[i];
    float sum = 0.f;
    for (int k = e - d; k < e; ++k) sum += sx[eidx[k]];
    float t = sum * nd[i];
    float nsv = ns[i];
    float x0 = fmaxf(t * W1[0] + b1[0], 0.f) * nsv;
    float x1 = fmaxf(t * W1[1] + b1[1], 0.f) * nsv;
    float x2 = fmaxf(t * W1[2] + b1[2], 0.f) * nsv;
    float x3 = fmaxf(t * W1[3] + b1[3], 0.f) * nsv;
    float4 o;
    o.x = x0*W2[0] + x1*W2[4] + x2*W2[8]  + x3*W2[12];
    o.y = x0*W2[1] + x1*W2[5] + x2*W2[9]  + x3*W2[13];
    o.z = x0*W2[2] + x1*W2[6] + x2*W2[10] + x3*W2[14];
    o.w = x0*W2[3] + x1*W2[7] + x2*W2[11] + x3*W2[15];
    A[i] = o;
}

__global__ void fb_g4(const float4* __restrict__ H, const int* __restrict__ eidx,
                      const int* __restrict__ endp, const int* __restrict__ deg,
                      const float* __restrict__ ns, const float* __restrict__ nd,
                      const float* __restrict__ b, const float* __restrict__ W,
                      float4* __restrict__ out, int N) {
    int i = blockIdx.x * blockDim.x + threadIdx.x;
    if (i >= N) return;
    int e = endp[i], d = deg[i];
    float s0 = 0.f, s1 = 0.f, s2 = 0.f, s3 = 0.f;
    for (int k = e - d; k < e; ++k) {
        float4 v = H[eidx[k]];
        s0 += v.x; s1 += v.y; s2 += v.z; s3 += v.w;
    }
    float nv = nd[i], nsv = ns[i];
    float x0 = fmaxf(s0 * nv + b[0], 0.f) * nsv;
    float x1 = fmaxf(s1 * nv + b[1], 0.f) * nsv;
    float x2 = fmaxf(s2 * nv + b[2], 0.f) * nsv;
    float x3 = fmaxf(s3 * nv + b[3], 0.f) * nsv;
    float4 o;
    o.x = x0*W[0] + x1*W[4] + x2*W[8]  + x3*W[12];
    o.y = x0*W[1] + x1*W[5] + x2*W[9]  + x3*W[13];
    o.z = x0*W[2] + x1*W[6] + x2*W[10] + x3*W[14];
    o.w = x0*W[3] + x1*W[7] + x2*W[11] + x3*W[15];
    out[i] = o;
}

__global__ void fb_gF(const float4* __restrict__ H, const int* __restrict__ eidx,
                      const int* __restrict__ endp, const int* __restrict__ deg,
                      const float* __restrict__ nd, const float* __restrict__ b,
                      const float* __restrict__ Wl, const float* __restrict__ bl,
                      float2* __restrict__ out, int N) {
    int i = blockIdx.x * blockDim.x + threadIdx.x;
    if (i >= N) return;
    int e = endp[i], d = deg[i];
    float s0 = 0.f, s1 = 0.f, s2 = 0.f, s3 = 0.f;
    for (int k = e - d; k < e; ++k) {
        float4 v = H[eidx[k]];
        s0 += v.x; s1 += v.y; s2 += v.z; s3 += v.w;
    }
    float nv = nd[i];
    float x0 = s0 * nv + b[0];
    float x1 = s1 * nv + b[1];
    float x2 = s2 * nv + b[2];
    float x3 = s3 * nv + b[3];
    float z0 = x0*Wl[0] + x1*Wl[2] + x2*Wl[4] + x3*Wl[6] + bl[0];
    float z1 = x0*Wl[1] + x1*Wl[3] + x2*Wl[5] + x3*Wl[7] + bl[1];
    float m  = fmaxf(z0, z1);
    float e0 = expf(z0 - m), e1 = expf(z1 - m);
    float inv = 1.f / (e0 + e1);
    out[i] = make_float2(e0 * inv, e1 * inv);
}

extern "C" void kernel_launch(void* const* d_in, const int* in_sizes, int n_in,
                              void* d_out, int out_size, void* d_ws, size_t ws_size,
                              hipStream_t stream) {
    const float* in_feat = (const float*)d_in[0];
    const int*   src     = (const int*)d_in[1];
    const int*   dst     = (const int*)d_in[2];
    const float* W1 = (const float*)d_in[3];
    const float* b1 = (const float*)d_in[4];
    const float* W2 = (const float*)d_in[5];
    const float* b2 = (const float*)d_in[6];
    const float* W3 = (const float*)d_in[7];
    const float* b3 = (const float*)d_in[8];
    const float* Wl = (const float*)d_in[9];
    const float* bl = (const float*)d_in[10];

    const int N = in_sizes[0];
    const int E = in_sizes[1];

    const int gridN = (N + BT - 1) / BT;
    const int gridE = (E + BT - 1) / BT;

    const int K    = (N + NPB - 1) / NPB;
    const int NBLK = (E + CH - 1) / CH;
    const size_t uN = (size_t)N, uE = (size_t)E;

    // Workspace (4B units):
    //  ns[N] | nd[N] | sx[N] | ctr[4*1032] | P[E] | R2[8N]
    //  R2 lifetime 1: P2 (E ushort = (E+1)/2 units) | M1,M2 (K*NBLK each)
    //  R2 lifetime 2: A (4N) | B4 (4N)
    const size_t SS = 4 * 1032;
    const size_t r2a = (uE + 1) / 2 + 2 * (size_t)K * NBLK;
    const size_t r2need = (8 * uN > r2a) ? 8 * uN : r2a;
    const size_t need4 = (3 * uN + SS + uE + r2need) * 4;

    if (ws_size >= need4 && N <= (1 << 20) && K <= KMAX) {
        float* ws   = (float*)d_ws;
        float* ns   = ws;
        float* nd   = ws + uN;
        float* sx   = ws + 2 * uN;
        int*   ctr  = (int*)(ws + 3 * uN);
        int* bsum1  = ctr;
        int* bsum2  = ctr + 1032;
        int* bbase1 = ctr + 2064;
        int* bbase2 = ctr + 3096;
        int*   P    = (int*)(ws + 3 * uN + SS);
        int*   R2   = P + uE;
        unsigned short* P2 = (unsigned short*)R2;
        int*   M1   = R2 + (uE + 1) / 2;
        int*   M2   = M1 + (size_t)K * NBLK;
        float4* A   = (float4*)R2;
        float4* B4  = (float4*)(R2 + 4 * uN);

        hist_kernel<<<NBLK, BT, 0, stream>>>(src, dst, M1, M2, E, K, NBLK);
        rowscan_kernel<<<K, 64, 0, stream>>>(M1, M2, bsum1, bsum2, NBLK);
        scanK_kernel<<<1, 1024, 0, stream>>>(bsum1, bbase1, bsum2, bbase2, K);
        rank_kernel<<<NBLK, BT, 0, stream>>>(src, dst, M1, M2, bbase1, bbase2, P, P2, E, K, NBLK);
        sdeg_kernel<<<K, BT, 0, stream>>>(P2, bbase2, in_feat, ns, sx, N);
        g1_kernel<<<K, BT, 0, stream>>>(P, bbase1, sx, ns, nd, W1, b1, W2, A, N);
        g4_kernel<<<K, BT, 0, stream>>>(P, bbase1, A, ns, nd, b2, W3, B4, N);
        gF_kernel<<<K, BT, 0, stream>>>(P, bbase1, B4, nd, b3, Wl, bl, (float2*)d_out, N);
        return;
    }

    // ---------- round-2 fallback ----------
    size_t need2 = (13 * uN + uE + 16) * 4;
    if (ws_size >= need2) {
        float* ws   = (float*)d_ws;
        float* ns   = ws;
        float* nd   = ws + uN;
        float* sx   = ws + 2 * uN;
        int*   deg  = (int*)(ws + 3 * uN);
        int*   start= (int*)(ws + 4 * uN);
        float4* A   = (float4*)(ws + 5 * uN);
        float4* B   = (float4*)(ws + 9 * uN);
        int*   eidx = (int*)(ws + 13 * uN);
        int*   cursor = eidx + uE;
        int*   degs = (int*)A;

        hipMemsetAsync(deg, 0, uN * sizeof(int), stream);
        hipMemsetAsync(degs, 0, uN * sizeof(int), stream);
        hipMemsetAsync(cursor, 0, sizeof(int), stream);
        count_kernel<<<gridE, BT, 0, stream>>>(src, dst, degs, deg, E);
        finalize_alloc_kernel<<<gridN, BT, 0, stream>>>(degs, deg, in_feat, ns, nd, sx, start, cursor, N);
        fill_kernel<<<gridE, BT, 0, stream>>>(src, dst, start, eidx, E);
        fb_g1<<<gridN, BT, 0, stream>>>(sx, eidx, start, deg, ns, nd, W1, b1, W2, A, N);
        fb_g4<<<gridN, BT, 0, stream>>>(A, eidx, start, deg, ns, nd, b2, W3, B, N);
        fb_gF<<<gridN, BT, 0, stream>>>(B, eidx, start, deg, nd, b3, Wl, bl, (float2*)d_out, N);
    }
}